// Round 1
// baseline (287.108 us; speedup 1.0000x reference)
//
#include <hip/hip_runtime.h>
#include <hip/hip_bf16.h>

#define NN 100000
#define NE 1600000
#define NF 128
#define UU 64

// ---------------- workspace layout (bytes) ----------------
// flag:      [0, 256)
// dst32:     [256, 256+6.4M)
// src32:     next 6.4M
// h:         next 25.6M   (NN*64 floats)
// a_dst:     next 0.4M
// a_src:     next 0.4M
// row_start: next 400004  (NN+1 ints)
static const size_t OFF_FLAG = 0;
static const size_t OFF_DST  = 256;
static const size_t OFF_SRC  = OFF_DST + (size_t)NE * 4;
static const size_t OFF_H    = OFF_SRC + (size_t)NE * 4;
static const size_t OFF_AD   = OFF_H   + (size_t)NN * UU * 4;
static const size_t OFF_AS   = OFF_AD  + (size_t)NN * 4;
static const size_t OFF_ROW  = OFF_AS  + (size_t)NN * 4;

// Detect whether edges buffer is int64 (odd 32-bit words are high halves == 0)
// or int32 (odd words are src/dst values, ~never all zero at these offsets).
__global__ void detect_fmt(const int* __restrict__ ew, int* __restrict__ flag) {
    if (threadIdx.x == 0 && blockIdx.x == 0) {
        int a = ew[2 * 400000 + 1] | ew[2 * 800000 + 1] |
                ew[2 * 1200000 + 1] | ew[2 * 1599999 + 1];
        *flag = (a == 0) ? 1 : 0;   // 1 => int64
    }
}

__global__ __launch_bounds__(256) void unpack_edges(const void* __restrict__ edges,
                                                    const int* __restrict__ flag,
                                                    int* __restrict__ dst,
                                                    int* __restrict__ src) {
    int i = blockIdx.x * blockDim.x + threadIdx.x;
    if (i >= NE) return;
    if (*flag) {
        const long long* e = (const long long*)edges;
        dst[i] = (int)e[2 * i];
        src[i] = (int)e[2 * i + 1];
    } else {
        const int* e = (const int*)edges;
        dst[i] = e[2 * i];
        src[i] = e[2 * i + 1];
    }
}

// h = X @ W  (NN x 128 @ 128 x 64), plus per-node attention pre-terms
// a_dst[n] = h[n] . ka[0:64],  a_src[n] = h[n] . ka[64:128]
// Block: 256 threads = 4 waves; each wave handles 8 nodes (block: 32 nodes).
__global__ __launch_bounds__(256) void gemm_attn(const float* __restrict__ X,
                                                 const float* __restrict__ W,
                                                 const float* __restrict__ ka,
                                                 float* __restrict__ h,
                                                 float* __restrict__ a_dst,
                                                 float* __restrict__ a_src) {
    __shared__ float sW[NF * UU];      // 32 KB, layout [k][u]
    __shared__ float sX[32][NF];       // 16 KB
    int tid = threadIdx.x;
    for (int i = tid; i < NF * UU; i += 256) sW[i] = W[i];
    int base = blockIdx.x * 32;
    for (int i = tid; i < 32 * NF; i += 256) {
        int r = i >> 7, c = i & 127;
        int n = base + r;
        sX[r][c] = (n < NN) ? X[(size_t)n * NF + c] : 0.f;
    }
    __syncthreads();

    int u = tid & 63, w = tid >> 6;
    int m0 = w * 8;
    float acc[8] = {0, 0, 0, 0, 0, 0, 0, 0};
    for (int k = 0; k < NF; k += 4) {
        float w0 = sW[(k + 0) * UU + u];
        float w1 = sW[(k + 1) * UU + u];
        float w2 = sW[(k + 2) * UU + u];
        float w3 = sW[(k + 3) * UU + u];
#pragma unroll
        for (int m = 0; m < 8; m++) {
            float4 x4 = *(const float4*)&sX[m0 + m][k];
            acc[m] += x4.x * w0 + x4.y * w1 + x4.z * w2 + x4.w * w3;
        }
    }

    float kau = ka[u], kau2 = ka[64 + u];
#pragma unroll
    for (int m = 0; m < 8; m++) {
        int n = base + m0 + m;
        float t1 = acc[m] * kau;
        float t2 = acc[m] * kau2;
#pragma unroll
        for (int off = 32; off; off >>= 1) {
            t1 += __shfl_down(t1, off);
            t2 += __shfl_down(t2, off);
        }
        if (n < NN) {
            h[(size_t)n * UU + u] = acc[m];
            if (u == 0) { a_dst[n] = t1; a_src[n] = t2; }
        }
    }
}

// CSR row offsets by binary search over sorted dst
__global__ __launch_bounds__(256) void build_rows(const int* __restrict__ dst,
                                                  int* __restrict__ row_start) {
    int n = blockIdx.x * blockDim.x + threadIdx.x;
    if (n > NN) return;
    if (n == NN) { row_start[NN] = NE; return; }
    int lo = 0, hi = NE;
    while (lo < hi) {
        int mid = (lo + hi) >> 1;
        if (dst[mid] < n) lo = mid + 1; else hi = mid;
    }
    row_start[n] = lo;
}

__device__ __forceinline__ float edge_score(float ad, float as) {
    float sc = ad + as;
    sc = sc > 0.f ? sc : 0.2f * sc;
    sc = fminf(fmaxf(sc, -2.f), 2.f);
    return __expf(sc);
}

// One wave per node: softmax over its edge segment + weighted gather of h[src].
__global__ __launch_bounds__(256) void aggregate(const int* __restrict__ row_start,
                                                 const int* __restrict__ srcv,
                                                 const float* __restrict__ h,
                                                 const float* __restrict__ a_dst,
                                                 const float* __restrict__ a_src,
                                                 float* __restrict__ out) {
    int gid = blockIdx.x * blockDim.x + threadIdx.x;
    int n = gid >> 6;
    int lane = gid & 63;
    if (n >= NN) return;
    int s = row_start[n];
    int e = row_start[n + 1];
    int cnt = e - s;
    float ad = a_dst[n];

    if (cnt <= 64) {
        // common path (avg degree 16): edge data lives in this wave's registers
        float myscore = 0.f;
        int mysrc = 0;
        int idx = s + lane;
        if (idx < e) {
            mysrc = srcv[idx];
            myscore = edge_score(ad, a_src[mysrc]);
        }
        float t = myscore;
#pragma unroll
        for (int off = 32; off; off >>= 1) t += __shfl_down(t, off);
        float ssum = __shfl(t, 0);
        float inv = (cnt > 0) ? 1.f / ssum : 0.f;
        float acc = 0.f;
        for (int j = 0; j < cnt; j++) {
            float wj = __shfl(myscore, j) * inv;
            int sj = __shfl(mysrc, j);
            acc += wj * h[(size_t)sj * UU + lane];
        }
        out[(size_t)n * UU + lane] = acc;
    } else {
        // rare long-segment path
        float ssum = 0.f;
        for (int i = s + lane; i < e; i += 64) {
            ssum += edge_score(ad, a_src[srcv[i]]);
        }
#pragma unroll
        for (int off = 32; off; off >>= 1) ssum += __shfl_down(ssum, off);
        ssum = __shfl(ssum, 0);
        float inv = 1.f / ssum;
        float acc = 0.f;
        for (int c = s; c < e; c += 64) {
            int i = c + lane;
            int sv = 0;
            float sc = 0.f;
            if (i < e) { sv = srcv[i]; sc = edge_score(ad, a_src[sv]); }
            int lim = min(64, e - c);
            for (int j = 0; j < lim; j++) {
                float wj = __shfl(sc, j) * inv;
                int sj = __shfl(sv, j);
                acc += wj * h[(size_t)sj * UU + lane];
            }
        }
        out[(size_t)n * UU + lane] = acc;
    }
}

extern "C" void kernel_launch(void* const* d_in, const int* in_sizes, int n_in,
                              void* d_out, int out_size, void* d_ws, size_t ws_size,
                              hipStream_t stream) {
    const float* X  = (const float*)d_in[0];   // node_states (NN x 128)
    const void*  Ed = d_in[1];                 // edges (NE x 2), int32 or int64
    const float* W  = (const float*)d_in[2];   // kernel (128 x 64)
    const float* KA = (const float*)d_in[3];   // kernel_attention (128 x 1)
    float* out = (float*)d_out;

    char* ws = (char*)d_ws;
    int*   flag   = (int*)(ws + OFF_FLAG);
    int*   dst32  = (int*)(ws + OFF_DST);
    int*   src32  = (int*)(ws + OFF_SRC);
    float* h      = (float*)(ws + OFF_H);
    float* a_dst  = (float*)(ws + OFF_AD);
    float* a_src  = (float*)(ws + OFF_AS);
    int*   rows   = (int*)(ws + OFF_ROW);

    detect_fmt<<<1, 64, 0, stream>>>((const int*)Ed, flag);
    unpack_edges<<<(NE + 255) / 256, 256, 0, stream>>>(Ed, flag, dst32, src32);
    gemm_attn<<<(NN + 31) / 32, 256, 0, stream>>>(X, W, KA, h, a_dst, a_src);
    build_rows<<<(NN + 1 + 255) / 256, 256, 0, stream>>>(dst32, rows);
    aggregate<<<(NN * 64 + 255) / 256, 256, 0, stream>>>(rows, src32, h, a_dst, a_src, out);
}

// Round 2
// 182.772 us; speedup vs baseline: 1.5709x; 1.5709x over previous
//
#include <hip/hip_runtime.h>
#include <hip/hip_bf16.h>

#define NN 100000
#define NE 1600000
#define NF 128
#define UU 64

// ---------------- workspace layout (bytes) ----------------
static const size_t OFF_FLAG = 0;                               // 256
static const size_t OFF_SRC  = 256;                             // NE*4
static const size_t OFF_H2   = OFF_SRC + (size_t)NE * 4;        // NN*64*2 (bf16)
static const size_t OFF_AD   = OFF_H2  + (size_t)NN * UU * 2;   // NN*4
static const size_t OFF_AS   = OFF_AD  + (size_t)NN * 4;        // NN*4
static const size_t OFF_ROW  = OFF_AS  + (size_t)NN * 4;        // (NN+1)*4

// Edge buffer may be int64 (odd 32-bit words are zero high-halves) or int32.
__global__ void detect_fmt(const int* __restrict__ ew, int* __restrict__ flag) {
    if (threadIdx.x == 0 && blockIdx.x == 0) {
        int a = ew[2 * 400000 + 1] | ew[2 * 800000 + 1] |
                ew[2 * 1200000 + 1] | ew[2 * 1599999 + 1];
        *flag = (a == 0) ? 1 : 0;   // 1 => int64
    }
}

__device__ __forceinline__ unsigned bfpack(float a, float b) {
    unsigned ua = __float_as_uint(a), ub = __float_as_uint(b);
    ua = (ua + 0x7FFFu + ((ua >> 16) & 1u)) >> 16;
    ub = (ub + 0x7FFFu + ((ub >> 16) & 1u)) >> 16;
    return ua | (ub << 16);
}

#define GEMM_BLOCKS   391   // ceil(NN/256)
#define ROWS_BLOCKS   391   // ceil((NN+1)/256)
#define UNPACK_BLOCKS 1563  // ceil(NE/1024), 4 edges/thread

// mega kernel: [0,391) gemm+attn pre-terms, [391,782) CSR rows, [782,2345) src unpack
__global__ __launch_bounds__(256) void mega(const float* __restrict__ X,
                                            const void* __restrict__ edges,
                                            const int* __restrict__ flag,
                                            const float* __restrict__ W,
                                            const float* __restrict__ ka,
                                            unsigned short* __restrict__ h2,
                                            float* __restrict__ a_dst,
                                            float* __restrict__ a_src,
                                            int* __restrict__ src32,
                                            int* __restrict__ rows) {
    int bid = blockIdx.x;
    int tid = threadIdx.x;

    if (bid < GEMM_BLOCKS) {
        // ---- GEMM: h = X @ W, tile 256 nodes x 64 units, micro 8x8 ----
        __shared__ float sXT[32][260];   // [k][node], stride 260: 16B-aligned rows, 2-way banks
        __shared__ float sW4[32][64];    // [k][u]
        int n0 = bid * 256;
        int ug = tid & 7;          // unit group  -> u0 = ug*8
        int mg = tid >> 3;         // node group  -> m0 = mg*8
        int u0 = ug * 8, m0 = mg * 8;
        float acc[8][8] = {};

        for (int kc = 0; kc < NF; kc += 32) {
            { // stage W chunk (2048 floats)
                const float4* Wg = (const float4*)(W + kc * UU);
                float4* sWv = (float4*)(&sW4[0][0]);
                sWv[tid]       = Wg[tid];
                sWv[tid + 256] = Wg[tid + 256];
            }
            // stage X chunk transposed
            for (int t = 0; t < 8; t++) {
                int i = tid + t * 256;
                int nl = i >> 3;          // 0..255
                int c4 = i & 7;           // float4 idx within 32-float chunk
                int n = n0 + nl;
                float4 xv = make_float4(0.f, 0.f, 0.f, 0.f);
                if (n < NN) xv = *(const float4*)(X + (size_t)n * NF + kc + c4 * 4);
                sXT[c4 * 4 + 0][nl] = xv.x;
                sXT[c4 * 4 + 1][nl] = xv.y;
                sXT[c4 * 4 + 2][nl] = xv.z;
                sXT[c4 * 4 + 3][nl] = xv.w;
            }
            __syncthreads();
            for (int k = 0; k < 32; k++) {
                float4 xa = *(const float4*)&sXT[k][m0];
                float4 xb = *(const float4*)&sXT[k][m0 + 4];
                float4 wa = *(const float4*)&sW4[k][u0];
                float4 wb = *(const float4*)&sW4[k][u0 + 4];
                float xs[8]  = {xa.x, xa.y, xa.z, xa.w, xb.x, xb.y, xb.z, xb.w};
                float wsv[8] = {wa.x, wa.y, wa.z, wa.w, wb.x, wb.y, wb.z, wb.w};
#pragma unroll
                for (int i = 0; i < 8; i++)
#pragma unroll
                    for (int j = 0; j < 8; j++)
                        acc[i][j] += xs[i] * wsv[j];
            }
            __syncthreads();
        }

        // epilogue: pack h to bf16, compute attention pre-terms
        float4 ka0 = *(const float4*)(ka + u0);
        float4 ka1 = *(const float4*)(ka + u0 + 4);
        float4 kb0 = *(const float4*)(ka + 64 + u0);
        float4 kb1 = *(const float4*)(ka + 64 + u0 + 4);
#pragma unroll
        for (int i = 0; i < 8; i++) {
            int n = n0 + m0 + i;
            if (n < NN) {
                uint4 pk;
                pk.x = bfpack(acc[i][0], acc[i][1]);
                pk.y = bfpack(acc[i][2], acc[i][3]);
                pk.z = bfpack(acc[i][4], acc[i][5]);
                pk.w = bfpack(acc[i][6], acc[i][7]);
                *(uint4*)(h2 + (size_t)n * UU + u0) = pk;
            }
            float pd = acc[i][0] * ka0.x + acc[i][1] * ka0.y + acc[i][2] * ka0.z + acc[i][3] * ka0.w
                     + acc[i][4] * ka1.x + acc[i][5] * ka1.y + acc[i][6] * ka1.z + acc[i][7] * ka1.w;
            float ps = acc[i][0] * kb0.x + acc[i][1] * kb0.y + acc[i][2] * kb0.z + acc[i][3] * kb0.w
                     + acc[i][4] * kb1.x + acc[i][5] * kb1.y + acc[i][6] * kb1.z + acc[i][7] * kb1.w;
            pd += __shfl_xor(pd, 1); pd += __shfl_xor(pd, 2); pd += __shfl_xor(pd, 4);
            ps += __shfl_xor(ps, 1); ps += __shfl_xor(ps, 2); ps += __shfl_xor(ps, 4);
            if (ug == 0 && n < NN) { a_dst[n] = pd; a_src[n] = ps; }
        }
        return;
    }
    bid -= GEMM_BLOCKS;

    if (bid < ROWS_BLOCKS) {
        // ---- CSR row offsets by binary search on ORIGINAL edges ----
        int n = bid * 256 + tid;
        if (n > NN) return;
        if (n == NN) { rows[NN] = NE; return; }
        int fl = *flag;
        const int* ew = (const int*)edges;
        int lo = 0, hi = NE;
        while (lo < hi) {
            int mid = (lo + hi) >> 1;
            int d = fl ? ew[4 * (size_t)mid] : ew[2 * (size_t)mid];
            if (d < n) lo = mid + 1; else hi = mid;
        }
        rows[n] = lo;
        return;
    }
    bid -= ROWS_BLOCKS;

    // ---- unpack src ----
    {
        int fl = *flag;
        const int* ew = (const int*)edges;
#pragma unroll
        for (int t = 0; t < 4; t++) {
            int i = bid * 1024 + t * 256 + tid;
            if (i < NE) src32[i] = fl ? ew[4 * (size_t)i + 2] : ew[2 * (size_t)i + 1];
        }
    }
}

__device__ __forceinline__ float edge_score(float ad, float as) {
    float sc = ad + as;
    sc = sc > 0.f ? sc : 0.2f * sc;
    sc = fminf(fmaxf(sc, -2.f), 2.f);
    return __expf(sc);
}

// One wave per node; gather uses 16-lane float4 groups -> 4 edges per load step.
__global__ __launch_bounds__(256) void aggregate(const int* __restrict__ rows,
                                                 const int* __restrict__ srcv,
                                                 const unsigned short* __restrict__ h2,
                                                 const float* __restrict__ a_dst,
                                                 const float* __restrict__ a_src,
                                                 float* __restrict__ out) {
    int gid = blockIdx.x * blockDim.x + threadIdx.x;
    int n = gid >> 6;
    int lane = gid & 63;
    if (n >= NN) return;
    int s = rows[n], e = rows[n + 1];
    int cnt = e - s;
    float ad = a_dst[n];
    int g = lane >> 4, gl = lane & 15;
    float4 acc = make_float4(0.f, 0.f, 0.f, 0.f);

    if (cnt <= 64) {
        int idx = s + lane;
        int mysrc = 0; float myscore = 0.f;
        if (idx < e) { mysrc = srcv[idx]; myscore = edge_score(ad, a_src[mysrc]); }
        float t = myscore;
#pragma unroll
        for (int off = 32; off; off >>= 1) t += __shfl_xor(t, off);
        float inv = (cnt > 0) ? 1.f / t : 0.f;
        for (int c = 0; c < cnt; c += 4) {
            int j = c + g;                         // j>=cnt lanes: score 0, src 0 (safe)
            float wj = __shfl(myscore, j) * inv;
            int sj = __shfl(mysrc, j);
            uint2 r = *(const uint2*)(h2 + (size_t)sj * UU + gl * 4);
            acc.x += wj * __uint_as_float(r.x << 16);
            acc.y += wj * __uint_as_float(r.x & 0xFFFF0000u);
            acc.z += wj * __uint_as_float(r.y << 16);
            acc.w += wj * __uint_as_float(r.y & 0xFFFF0000u);
        }
    } else {
        float ssum = 0.f;
        for (int i = s + lane; i < e; i += 64) ssum += edge_score(ad, a_src[srcv[i]]);
#pragma unroll
        for (int off = 32; off; off >>= 1) ssum += __shfl_xor(ssum, off);
        float inv = 1.f / ssum;
        for (int c = s; c < e; c += 64) {
            int i = c + lane;
            int mysrc = 0; float myscore = 0.f;
            if (i < e) { mysrc = srcv[i]; myscore = edge_score(ad, a_src[mysrc]); }
            int lim = min(64, e - c);
            for (int c2 = 0; c2 < lim; c2 += 4) {
                int j = c2 + g;
                float wj = __shfl(myscore, j) * inv;
                int sj = __shfl(mysrc, j);
                uint2 r = *(const uint2*)(h2 + (size_t)sj * UU + gl * 4);
                acc.x += wj * __uint_as_float(r.x << 16);
                acc.y += wj * __uint_as_float(r.x & 0xFFFF0000u);
                acc.z += wj * __uint_as_float(r.y << 16);
                acc.w += wj * __uint_as_float(r.y & 0xFFFF0000u);
            }
        }
    }
    // combine the 4 edge-groups
    acc.x += __shfl_xor(acc.x, 32); acc.y += __shfl_xor(acc.y, 32);
    acc.z += __shfl_xor(acc.z, 32); acc.w += __shfl_xor(acc.w, 32);
    acc.x += __shfl_xor(acc.x, 16); acc.y += __shfl_xor(acc.y, 16);
    acc.z += __shfl_xor(acc.z, 16); acc.w += __shfl_xor(acc.w, 16);
    if (lane < 16) *(float4*)(out + (size_t)n * UU + gl * 4) = acc;
}

extern "C" void kernel_launch(void* const* d_in, const int* in_sizes, int n_in,
                              void* d_out, int out_size, void* d_ws, size_t ws_size,
                              hipStream_t stream) {
    const float* X  = (const float*)d_in[0];
    const void*  Ed = d_in[1];
    const float* W  = (const float*)d_in[2];
    const float* KA = (const float*)d_in[3];
    float* out = (float*)d_out;

    char* ws = (char*)d_ws;
    int*            flag  = (int*)(ws + OFF_FLAG);
    int*            src32 = (int*)(ws + OFF_SRC);
    unsigned short* h2    = (unsigned short*)(ws + OFF_H2);
    float*          a_dst = (float*)(ws + OFF_AD);
    float*          a_src = (float*)(ws + OFF_AS);
    int*            rows  = (int*)(ws + OFF_ROW);

    detect_fmt<<<1, 64, 0, stream>>>((const int*)Ed, flag);
    mega<<<GEMM_BLOCKS + ROWS_BLOCKS + UNPACK_BLOCKS, 256, 0, stream>>>(
        X, Ed, flag, W, KA, h2, a_dst, a_src, src32, rows);
    aggregate<<<(NN * 64 + 255) / 256, 256, 0, stream>>>(rows, src32, h2, a_dst, a_src, out);
}

// Round 3
// 166.557 us; speedup vs baseline: 1.7238x; 1.0974x over previous
//
#include <hip/hip_runtime.h>
#include <hip/hip_bf16.h>

#define NN 100000
#define NE 1600000
#define NF 128
#define UU 64

typedef __attribute__((ext_vector_type(8))) short short8;
typedef __attribute__((ext_vector_type(4))) float f32x4;

// ---------------- workspace layout (bytes) ----------------
static const size_t OFF_FLAG = 0;                               // 256
static const size_t OFF_SRC  = 256;                             // NE*4
static const size_t OFF_H2   = OFF_SRC + (size_t)NE * 4;        // NN*64*2 (bf16)
static const size_t OFF_AD   = OFF_H2  + (size_t)NN * UU * 2;   // NN*4
static const size_t OFF_AS   = OFF_AD  + (size_t)NN * 4;        // NN*4
static const size_t OFF_ROW  = OFF_AS  + (size_t)NN * 4;        // (NN+1)*4
static const size_t OFF_WP   = OFF_ROW + (size_t)(NN + 1) * 4;  // 8192 bf16 (16KB)

__device__ __forceinline__ unsigned short bfr(float v) {
    unsigned u = __float_as_uint(v);
    return (unsigned short)((u + 0x7FFFu + ((u >> 16) & 1u)) >> 16);
}

// prep: edge-format flag + W packed into MFMA B-fragment-linear bf16 layout.
// Wp[(((nt*4+kb)*4+quad)*16 + l15)*8 + j] = bf16(W[(kb*32+quad*8+j)*64 + nt*16 + l15])
__global__ __launch_bounds__(256) void prep(const int* __restrict__ ew,
                                            const float* __restrict__ W,
                                            int* __restrict__ flag,
                                            unsigned short* __restrict__ Wp) {
    if (threadIdx.x == 0) {
        int a = ew[2 * 400000 + 1] | ew[2 * 800000 + 1] |
                ew[2 * 1200000 + 1] | ew[2 * 1599999 + 1];
        *flag = (a == 0) ? 1 : 0;   // 1 => int64
    }
    for (int i = threadIdx.x; i < 8192; i += 256) {
        int j   = i & 7;
        int l15 = (i >> 3) & 15;
        int quad = (i >> 7) & 3;
        int kb  = (i >> 9) & 3;
        int nt  = i >> 11;
        Wp[i] = bfr(W[(size_t)(kb * 32 + quad * 8 + j) * UU + nt * 16 + l15]);
    }
}

#define GEMM_BLOCKS   1563  // ceil(NN/64)
#define ROWS_BLOCKS   391   // ceil((NN+1)/256)
#define UNPACK_BLOCKS 1563  // ceil(NE/1024)

__global__ __launch_bounds__(256) void mega(const float* __restrict__ X,
                                            const void* __restrict__ edges,
                                            const int* __restrict__ flag,
                                            const unsigned short* __restrict__ Wp,
                                            const float* __restrict__ ka,
                                            unsigned short* __restrict__ h2,
                                            float* __restrict__ a_dst,
                                            float* __restrict__ a_src,
                                            int* __restrict__ src32,
                                            int* __restrict__ rows) {
    int bid = blockIdx.x;
    int tid = threadIdx.x;

    if (bid < GEMM_BLOCKS) {
        // ---- MFMA GEMM: h = X @ W. Block = 64 nodes (4 waves x 16). ----
        int wv = tid >> 6, lane = tid & 63;
        int quad = lane >> 4, l15 = lane & 15;
        int nb = bid * 64 + wv * 16;
        int row = nb + l15; if (row >= NN) row = NN - 1;   // clamped rows: stores guarded
        const float* xr = X + (size_t)row * NF + quad * 8;

        // A fragments: A[m=l15][k=quad*8+j], 8 contiguous f32 -> bf16
        short8 afrag[4];
#pragma unroll
        for (int kb = 0; kb < 4; kb++) {
            float4 p0 = *(const float4*)(xr + kb * 32);
            float4 p1 = *(const float4*)(xr + kb * 32 + 4);
            short8 a;
            a[0] = (short)bfr(p0.x); a[1] = (short)bfr(p0.y);
            a[2] = (short)bfr(p0.z); a[3] = (short)bfr(p0.w);
            a[4] = (short)bfr(p1.x); a[5] = (short)bfr(p1.y);
            a[6] = (short)bfr(p1.z); a[7] = (short)bfr(p1.w);
            afrag[kb] = a;
        }

        f32x4 acc[4] = {f32x4{0,0,0,0}, f32x4{0,0,0,0}, f32x4{0,0,0,0}, f32x4{0,0,0,0}};
        const short8* wpf = (const short8*)Wp;
#pragma unroll
        for (int nt = 0; nt < 4; nt++) {
#pragma unroll
            for (int kb = 0; kb < 4; kb++) {
                short8 b = wpf[((nt * 4 + kb) * 4 + quad) * 16 + l15];
                acc[nt] = __builtin_amdgcn_mfma_f32_16x16x32_bf16(afrag[kb], b, acc[nt], 0, 0, 0);
            }
        }

        // epilogue: C/D layout col=l15 (u = nt*16+l15), row m = nb + quad*4 + reg
        float kad[4], kas[4];
#pragma unroll
        for (int nt = 0; nt < 4; nt++) {
            kad[nt] = ka[nt * 16 + l15];
            kas[nt] = ka[64 + nt * 16 + l15];
        }
#pragma unroll
        for (int r = 0; r < 4; r++) {
            int m = nb + quad * 4 + r;
            if (m < NN) {
#pragma unroll
                for (int nt = 0; nt < 4; nt++)
                    h2[(size_t)m * UU + nt * 16 + l15] = bfr(acc[nt][r]);
            }
            float pd = acc[0][r] * kad[0] + acc[1][r] * kad[1] + acc[2][r] * kad[2] + acc[3][r] * kad[3];
            float ps = acc[0][r] * kas[0] + acc[1][r] * kas[1] + acc[2][r] * kas[2] + acc[3][r] * kas[3];
            pd += __shfl_xor(pd, 1); pd += __shfl_xor(pd, 2);
            pd += __shfl_xor(pd, 4); pd += __shfl_xor(pd, 8);
            ps += __shfl_xor(ps, 1); ps += __shfl_xor(ps, 2);
            ps += __shfl_xor(ps, 4); ps += __shfl_xor(ps, 8);
            if (l15 == 0 && m < NN) { a_dst[m] = pd; a_src[m] = ps; }
        }
        return;
    }
    bid -= GEMM_BLOCKS;

    if (bid < ROWS_BLOCKS) {
        // ---- CSR row offsets by binary search on ORIGINAL edges ----
        int n = bid * 256 + tid;
        if (n > NN) return;
        if (n == NN) { rows[NN] = NE; return; }
        int fl = *flag;
        const int* ew = (const int*)edges;
        int lo = 0, hi = NE;
        while (lo < hi) {
            int mid = (lo + hi) >> 1;
            int d = fl ? ew[4 * (size_t)mid] : ew[2 * (size_t)mid];
            if (d < n) lo = mid + 1; else hi = mid;
        }
        rows[n] = lo;
        return;
    }
    bid -= ROWS_BLOCKS;

    // ---- unpack src ----
    {
        int fl = *flag;
        const int* ew = (const int*)edges;
#pragma unroll
        for (int t = 0; t < 4; t++) {
            int i = bid * 1024 + t * 256 + tid;
            if (i < NE) src32[i] = fl ? ew[4 * (size_t)i + 2] : ew[2 * (size_t)i + 1];
        }
    }
}

__device__ __forceinline__ float edge_score(float ad, float as) {
    float sc = ad + as;
    sc = sc > 0.f ? sc : 0.2f * sc;
    sc = fminf(fmaxf(sc, -2.f), 2.f);
    return __expf(sc);
}

// One wave per node; gather uses 16-lane float4 groups -> 4 edges per load step.
__global__ __launch_bounds__(256) void aggregate(const int* __restrict__ rows,
                                                 const int* __restrict__ srcv,
                                                 const unsigned short* __restrict__ h2,
                                                 const float* __restrict__ a_dst,
                                                 const float* __restrict__ a_src,
                                                 float* __restrict__ out) {
    int gid = blockIdx.x * blockDim.x + threadIdx.x;
    int n = gid >> 6;
    int lane = gid & 63;
    if (n >= NN) return;
    int s = rows[n], e = rows[n + 1];
    int cnt = e - s;
    float ad = a_dst[n];
    int g = lane >> 4, gl = lane & 15;
    float4 acc = make_float4(0.f, 0.f, 0.f, 0.f);

    if (cnt <= 64) {
        int idx = s + lane;
        int mysrc = 0; float myscore = 0.f;
        if (idx < e) { mysrc = srcv[idx]; myscore = edge_score(ad, a_src[mysrc]); }
        float t = myscore;
#pragma unroll
        for (int off = 32; off; off >>= 1) t += __shfl_xor(t, off);
        float inv = (cnt > 0) ? 1.f / t : 0.f;
        for (int c = 0; c < cnt; c += 4) {
            int j = c + g;                         // j>=cnt lanes: score 0, src 0 (safe)
            float wj = __shfl(myscore, j) * inv;
            int sj = __shfl(mysrc, j);
            uint2 r = *(const uint2*)(h2 + (size_t)sj * UU + gl * 4);
            acc.x += wj * __uint_as_float(r.x << 16);
            acc.y += wj * __uint_as_float(r.x & 0xFFFF0000u);
            acc.z += wj * __uint_as_float(r.y << 16);
            acc.w += wj * __uint_as_float(r.y & 0xFFFF0000u);
        }
    } else {
        float ssum = 0.f;
        for (int i = s + lane; i < e; i += 64) ssum += edge_score(ad, a_src[srcv[i]]);
#pragma unroll
        for (int off = 32; off; off >>= 1) ssum += __shfl_xor(ssum, off);
        float inv = 1.f / ssum;
        for (int c = s; c < e; c += 64) {
            int i = c + lane;
            int mysrc = 0; float myscore = 0.f;
            if (i < e) { mysrc = srcv[i]; myscore = edge_score(ad, a_src[mysrc]); }
            int lim = min(64, e - c);
            for (int c2 = 0; c2 < lim; c2 += 4) {
                int j = c2 + g;
                float wj = __shfl(myscore, j) * inv;
                int sj = __shfl(mysrc, j);
                uint2 r = *(const uint2*)(h2 + (size_t)sj * UU + gl * 4);
                acc.x += wj * __uint_as_float(r.x << 16);
                acc.y += wj * __uint_as_float(r.x & 0xFFFF0000u);
                acc.z += wj * __uint_as_float(r.y << 16);
                acc.w += wj * __uint_as_float(r.y & 0xFFFF0000u);
            }
        }
    }
    acc.x += __shfl_xor(acc.x, 32); acc.y += __shfl_xor(acc.y, 32);
    acc.z += __shfl_xor(acc.z, 32); acc.w += __shfl_xor(acc.w, 32);
    acc.x += __shfl_xor(acc.x, 16); acc.y += __shfl_xor(acc.y, 16);
    acc.z += __shfl_xor(acc.z, 16); acc.w += __shfl_xor(acc.w, 16);
    if (lane < 16) *(float4*)(out + (size_t)n * UU + gl * 4) = acc;
}

extern "C" void kernel_launch(void* const* d_in, const int* in_sizes, int n_in,
                              void* d_out, int out_size, void* d_ws, size_t ws_size,
                              hipStream_t stream) {
    const float* X  = (const float*)d_in[0];
    const void*  Ed = d_in[1];
    const float* W  = (const float*)d_in[2];
    const float* KA = (const float*)d_in[3];
    float* out = (float*)d_out;

    char* ws = (char*)d_ws;
    int*            flag  = (int*)(ws + OFF_FLAG);
    int*            src32 = (int*)(ws + OFF_SRC);
    unsigned short* h2    = (unsigned short*)(ws + OFF_H2);
    float*          a_dst = (float*)(ws + OFF_AD);
    float*          a_src = (float*)(ws + OFF_AS);
    int*            rows  = (int*)(ws + OFF_ROW);
    unsigned short* Wp    = (unsigned short*)(ws + OFF_WP);

    prep<<<1, 256, 0, stream>>>((const int*)Ed, W, flag, Wp);
    mega<<<GEMM_BLOCKS + ROWS_BLOCKS + UNPACK_BLOCKS, 256, 0, stream>>>(
        X, Ed, flag, Wp, KA, h2, a_dst, a_src, src32, rows);
    aggregate<<<(NN * 64 + 255) / 256, 256, 0, stream>>>(rows, src32, h2, a_dst, a_src, out);
}